// Round 3
// baseline (259.923 us; speedup 1.0000x reference)
//
#include <hip/hip_runtime.h>

#define TID threadIdx.x

constexpr int B = 2, C = 256, N = 2048, H = 8, D = 32, BH = 16;
constexpr float EPS = 1e-5f;
constexpr float SCALE = 0.17677669529663687f; // 32^-0.5
constexpr size_t SZ = (size_t)BH * N * D;     // 1048576 floats per Q/K/V buffer

// ---------------- kernel 1: batchnorm stats (mean, rstd per channel) ----------------
__global__ __launch_bounds__(256) void k_bnstats(const float* __restrict__ x,
                                                 float* __restrict__ stats) {
  int c = blockIdx.x;
  float s = 0.f, ss = 0.f;
  const float4* x4 = (const float4*)x;
  for (int k = 0; k < B; ++k) {
    const float4* p = x4 + (size_t)(k * C + c) * (N / 4);
    for (int i = TID; i < N / 4; i += 256) {
      float4 v = p[i];
      s += v.x + v.y + v.z + v.w;
      ss += v.x * v.x + v.y * v.y + v.z * v.z + v.w * v.w;
    }
  }
#pragma unroll
  for (int off = 32; off; off >>= 1) {
    s += __shfl_down(s, off);
    ss += __shfl_down(ss, off);
  }
  __shared__ float red[8];
  int w = TID >> 6;
  if ((TID & 63) == 0) { red[w] = s; red[4 + w] = ss; }
  __syncthreads();
  if (TID == 0) {
    float S = red[0] + red[1] + red[2] + red[3];
    float SS = red[4] + red[5] + red[6] + red[7];
    float mean = S * (1.f / (B * N));
    float var = SS * (1.f / (B * N)) - mean * mean;
    stats[c] = mean;
    stats[C + c] = rsqrtf(var + EPS);
  }
}

// ---------------- kernel 2: fused BN-apply + grouped conv projections ----------------
// Writes Qa/Ka/Va directly in attention layout [bh][n][d] (d innermost), applying:
//   - the reference channel-split quirk: att (h,d) <- proj channel ch = d*8+h
//   - the q/k swap: Qa from wk, Ka from wq, Va from wv
// Qa[b,h,n,d] = sum_c wk[(d*8+h)*32 + c] * xn[b, ((d*8+h)>>5)*32 + c, n]
__global__ __launch_bounds__(256) void k_proj(const float* __restrict__ x,
    const float* __restrict__ gamma, const float* __restrict__ beta,
    const float* __restrict__ wk, const float* __restrict__ wq,
    const float* __restrict__ wv, const float* __restrict__ stats,
    float* __restrict__ ws) {
  // grid 768: proj = bid>>8 (0..2); rem: b = rem>>7, ntile = rem&127 (16 n's each)
  int proj = blockIdx.x >> 8;
  int rem = blockIdx.x & 255;
  int b = rem >> 7;
  int n0 = (rem & 127) * 16;
  const float* w = proj == 0 ? wk : (proj == 1 ? wq : wv);
  float* out = ws + 1024 + (size_t)proj * SZ;

  __shared__ float w_s[256 * 33];  // permuted: row (d + 32h) holds w[8d+h][*]
  __shared__ float xs[256 * 20];   // permuted: row (g + 8c) holds xn channel g*32+c

#pragma unroll
  for (int p = 0; p < 32; ++p) {
    int ch = p * 8 + (TID >> 5);
    int cc = TID & 31;
    float wval = w[ch * 32 + cc];
    int row = (ch >> 3) + ((ch & 7) << 5);  // d + 32h
    w_s[row * 33 + cc] = wval;
  }
#pragma unroll
  for (int p = 0; p < 16; ++p) {
    int cc = p * 16 + (TID >> 4);
    int nl = TID & 15;
    float v = x[(size_t)(b * C + cc) * N + n0 + nl];
    float a = stats[C + cc] * gamma[cc];
    float xn = (v - stats[cc]) * a + beta[cc];
    int row = (cc >> 5) + ((cc & 31) << 3);  // g + 8c
    xs[row * 20 + nl] = xn;
  }
  __syncthreads();

  int d = TID & 31;
  int t2 = TID >> 5;  // 0..7, n = n0 + t2*2 + {0,1}
#pragma unroll
  for (int h = 0; h < 8; ++h) {
    int g = (d * 8 + h) >> 5;
    const float* wrow = &w_s[(d + h * 32) * 33];
    float2 acc = {0.f, 0.f};
#pragma unroll
    for (int c = 0; c < 32; ++c) {
      float wv2 = wrow[c];
      float2 xv = *(const float2*)&xs[(g + c * 8) * 20 + t2 * 2];
      acc.x += wv2 * xv.x;
      acc.y += wv2 * xv.y;
    }
    size_t o = ((size_t)((b * 8 + h) * N) + n0 + t2 * 2) * D + d;
    out[o] = acc.x;
    out[o + D] = acc.y;
  }
}

// ---------------- kernel 3: flash attention (fp32), j-split for occupancy ----------------
__global__ __launch_bounds__(256, 2) void k_attn(const float* __restrict__ qa,
    const float* __restrict__ ka, const float* __restrict__ va,
    float* __restrict__ op, float* __restrict__ mp, float* __restrict__ lp, int JS) {
  int bid = blockIdx.x;
  int js = bid >> 7;       // grid = 128*JS, js outermost
  int rem = bid & 127;
  int bh = rem >> 3;
  int qt = rem & 7;
  int i = qt * 256 + TID;  // this thread's q row
  int jrange = N / JS;
  int ntiles = jrange / 64;

  const float4* Qp = (const float4*)(qa + ((size_t)(bh * N) + i) * D);
  float4 Q[8], O[8];
#pragma unroll
  for (int k = 0; k < 8; ++k) { Q[k] = Qp[k]; O[k] = make_float4(0.f, 0.f, 0.f, 0.f); }
  float m = -3.0e38f, l = 0.f;

  __shared__ float4 Ks[512], Vs[512];  // 64 rows x 32 d each
  const float4* Ksrc = (const float4*)ka + ((size_t)bh * N + (size_t)js * jrange) * 8;
  const float4* Vsrc = (const float4*)va + ((size_t)bh * N + (size_t)js * jrange) * 8;

  for (int t = 0; t < ntiles; ++t) {
    __syncthreads();
    Ks[TID] = Ksrc[t * 512 + TID];
    Ks[TID + 256] = Ksrc[t * 512 + TID + 256];
    Vs[TID] = Vsrc[t * 512 + TID];
    Vs[TID + 256] = Vsrc[t * 512 + TID + 256];
    __syncthreads();

    float s[64];
#pragma unroll
    for (int j = 0; j < 64; ++j) {
      const float4* K4 = &Ks[j * 8];
      float ax = 0.f, ay = 0.f, az = 0.f, aw = 0.f;
#pragma unroll
      for (int k = 0; k < 8; ++k) {
        float4 kv = K4[k];
        ax += kv.x * Q[k].x; ay += kv.y * Q[k].y;
        az += kv.z * Q[k].z; aw += kv.w * Q[k].w;
      }
      s[j] = (ax + ay + az + aw) * SCALE;
    }
    float mt = s[0];
#pragma unroll
    for (int j = 1; j < 64; ++j) mt = fmaxf(mt, s[j]);
    float mn = fmaxf(m, mt);
    float corr = __expf(m - mn);  // first tile: exp(-inf) = 0
    l *= corr;
#pragma unroll
    for (int k = 0; k < 8; ++k) {
      O[k].x *= corr; O[k].y *= corr; O[k].z *= corr; O[k].w *= corr;
    }
    float ls = 0.f;
#pragma unroll
    for (int j = 0; j < 64; ++j) { float pp = __expf(s[j] - mn); s[j] = pp; ls += pp; }
    l += ls;
#pragma unroll
    for (int j = 0; j < 64; ++j) {
      const float4* V4 = &Vs[j * 8];
      float pp = s[j];
#pragma unroll
      for (int k = 0; k < 8; ++k) {
        O[k].x += pp * V4[k].x; O[k].y += pp * V4[k].y;
        O[k].z += pp * V4[k].z; O[k].w += pp * V4[k].w;
      }
    }
    m = mn;
  }
  float4* Op4 = (float4*)(op + ((size_t)(js * BH + bh) * N + i) * D);
#pragma unroll
  for (int k = 0; k < 8; ++k) Op4[k] = O[k];
  mp[(size_t)(js * BH + bh) * N + i] = m;
  lp[(size_t)(js * BH + bh) * N + i] = l;
}

// ---------------- kernel 4: combine j-split partials, normalize, transpose ----------------
// ao[b, h*32+d, n] = (sum_s e^{m_s-m_g} O_s[bh,n,d]) / (sum_s e^{m_s-m_g} l_s)
__global__ __launch_bounds__(256) void k_combine(const float* __restrict__ op,
    const float* __restrict__ mp, const float* __restrict__ lp,
    float* __restrict__ ao, int JS) {
  int bh = blockIdx.x >> 3;
  int nc = blockIdx.x & 7;
  int n = nc * 256 + TID;
  int b = bh >> 3, h = bh & 7;
  float mv[4];
  float mg = -3.0e38f;
  for (int s = 0; s < JS; ++s) {
    mv[s] = mp[(size_t)(s * BH + bh) * N + n];
    mg = fmaxf(mg, mv[s]);
  }
  float wgt[4];
  float lg = 0.f;
  for (int s = 0; s < JS; ++s) {
    wgt[s] = __expf(mv[s] - mg);
    lg += wgt[s] * lp[(size_t)(s * BH + bh) * N + n];
  }
  float inv = 1.f / lg;
  for (int k = 0; k < 8; ++k) {
    float ox = 0.f, oy = 0.f, oz = 0.f, ow = 0.f;
    for (int s = 0; s < JS; ++s) {
      const float4 v = *(const float4*)(op + ((size_t)(s * BH + bh) * N + n) * D + k * 4);
      ox += wgt[s] * v.x; oy += wgt[s] * v.y; oz += wgt[s] * v.z; ow += wgt[s] * v.w;
    }
    size_t base = (size_t)(b * C + h * D + k * 4) * N + n;
    ao[base] = ox * inv;
    ao[base + N] = oy * inv;
    ao[base + 2 * N] = oz * inv;
    ao[base + 3 * N] = ow * inv;
  }
}

// ---------------- kernel 5: output 1x1 conv: out[b,o,n] = sum_c wo[o,c]*ao[b,c,n] + bo[o] ----------------
__global__ __launch_bounds__(256) void k_final(const float* __restrict__ ao,
    const float* __restrict__ wo, const float* __restrict__ bo,
    float* __restrict__ out) {
  // grid 1024: nt = bid&63 (n0 = nt*32), oq = (bid>>6)&7 (o0 = oq*32), b = bid>>9
  __shared__ float w_s[32 * 256];  // [o_local][c]
  __shared__ float a_s[256 * 32];  // [c][n_local]
  int nt = blockIdx.x & 63, oq = (blockIdx.x >> 6) & 7, b = blockIdx.x >> 9;
  int n0 = nt * 32, o0 = oq * 32;
#pragma unroll
  for (int p = 0; p < 8; ++p) {
    int idx = p * 256 + TID;
    int o_l = idx >> 6, c4 = idx & 63;
    ((float4*)w_s)[o_l * 64 + c4] = ((const float4*)wo)[(o0 + o_l) * 64 + c4];
  }
#pragma unroll
  for (int p = 0; p < 8; ++p) {
    int idx = p * 256 + TID;
    int c = idx >> 3, n4 = idx & 7;
    ((float4*)a_s)[c * 8 + n4] =
        *(const float4*)(ao + (size_t)(b * C + c) * N + n0 + n4 * 4);
  }
  __syncthreads();
  int n_l = TID & 31, og = TID >> 5;  // thread covers o = o0 + og*4 + k
  float acc[4] = {0.f, 0.f, 0.f, 0.f};
  for (int c = 0; c < 256; ++c) {
    float av = a_s[c * 32 + n_l];
#pragma unroll
    for (int k = 0; k < 4; ++k) acc[k] += w_s[(og * 4 + k) * 256 + c] * av;
  }
#pragma unroll
  for (int k = 0; k < 4; ++k) {
    int o = o0 + og * 4 + k;
    out[(size_t)(b * C + o) * N + n0 + n_l] = acc[k] + bo[o];
  }
}

extern "C" void kernel_launch(void* const* d_in, const int* in_sizes, int n_in,
                              void* d_out, int out_size, void* d_ws, size_t ws_size,
                              hipStream_t stream) {
  const float* x = (const float*)d_in[0];
  const float* gamma = (const float*)d_in[1];
  const float* beta = (const float*)d_in[2];
  const float* wk = (const float*)d_in[3];
  const float* wq = (const float*)d_in[4];
  const float* wv = (const float*)d_in[5];
  const float* wo = (const float*)d_in[6];
  const float* bo = (const float*)d_in[7];
  float* out = (float*)d_out;
  float* ws = (float*)d_ws;

  // workspace floats needed: stats(1024 pad) + 3*SZ (qkv) + JS*SZ (Opart)
  //                          + 2*JS*BH*N (m,l) + SZ (ao)
  auto need = [](int js) {
    return (size_t)(1024 + (size_t)(4 + js) * SZ + (size_t)js * 2 * BH * N) * 4;
  };
  int JS = 4;
  while (JS > 1 && need(JS) > ws_size) JS >>= 1;

  float* stats = ws;
  float* qa = ws + 1024;
  float* ka = qa + SZ;
  float* va = ka + SZ;
  float* op = va + SZ;
  float* mp = op + (size_t)JS * SZ;
  float* lp = mp + (size_t)JS * BH * N;
  float* ao = lp + (size_t)JS * BH * N;

  k_bnstats<<<256, 256, 0, stream>>>(x, stats);
  k_proj<<<768, 256, 0, stream>>>(x, gamma, beta, wk, wq, wv, stats, ws);
  k_attn<<<128 * JS, 256, 0, stream>>>(qa, ka, va, op, mp, lp, JS);
  k_combine<<<128, 256, 0, stream>>>(op, mp, lp, ao, JS);
  k_final<<<1024, 256, 0, stream>>>(ao, wo, bo, out);
}

// Round 4
// 89.213 us; speedup vs baseline: 2.9135x; 2.9135x over previous
//
#include <hip/hip_runtime.h>

#define TID threadIdx.x

constexpr int B = 2, C = 256, N = 2048, H = 8, D = 32, BH = 16;
constexpr float EPS = 1e-5f;
constexpr float SCALE = 0.17677669529663687f; // 32^-0.5
constexpr size_t SZ = (size_t)BH * N * D;     // 1048576 elements per Q/K/V buffer

typedef _Float16 h8 __attribute__((ext_vector_type(8)));
typedef _Float16 h4 __attribute__((ext_vector_type(4)));
typedef float f32x4 __attribute__((ext_vector_type(4)));

// ---------------- kernel 1: batchnorm stats (mean, rstd per channel) ----------------
__global__ __launch_bounds__(256) void k_bnstats(const float* __restrict__ x,
                                                 float* __restrict__ stats) {
  int c = blockIdx.x;
  float s = 0.f, ss = 0.f;
  const float4* x4 = (const float4*)x;
  for (int k = 0; k < B; ++k) {
    const float4* p = x4 + (size_t)(k * C + c) * (N / 4);
    for (int i = TID; i < N / 4; i += 256) {
      float4 v = p[i];
      s += v.x + v.y + v.z + v.w;
      ss += v.x * v.x + v.y * v.y + v.z * v.z + v.w * v.w;
    }
  }
#pragma unroll
  for (int off = 32; off; off >>= 1) {
    s += __shfl_down(s, off);
    ss += __shfl_down(ss, off);
  }
  __shared__ float red[8];
  int w = TID >> 6;
  if ((TID & 63) == 0) { red[w] = s; red[4 + w] = ss; }
  __syncthreads();
  if (TID == 0) {
    float S = red[0] + red[1] + red[2] + red[3];
    float SS = red[4] + red[5] + red[6] + red[7];
    float mean = S * (1.f / (B * N));
    float var = SS * (1.f / (B * N)) - mean * mean;
    stats[c] = mean;
    stats[C + c] = rsqrtf(var + EPS);
  }
}

// ---------------- kernel 2: fused BN-apply + grouped conv projections (fp16 out) --------
// Qa/Ka: fp16 [bh][n][d];  Va: fp16 TRANSPOSED [bh][d][n]  (for V^T MFMA A-fragments)
// Applies channel-split quirk (att (h,d) <- proj channel d*8+h) and q/k swap.
__global__ __launch_bounds__(256) void k_proj(const float* __restrict__ x,
    const float* __restrict__ gamma, const float* __restrict__ beta,
    const float* __restrict__ wk, const float* __restrict__ wq,
    const float* __restrict__ wv, const float* __restrict__ stats,
    _Float16* __restrict__ qa, _Float16* __restrict__ ka, _Float16* __restrict__ va) {
  int proj = blockIdx.x >> 8;
  int rem = blockIdx.x & 255;
  int b = rem >> 7;
  int n0 = (rem & 127) * 16;
  const float* w = proj == 0 ? wk : (proj == 1 ? wq : wv);
  _Float16* out = proj == 0 ? qa : (proj == 1 ? ka : va);

  __shared__ float w_s[256 * 33];  // row (d + 32h) holds w[8d+h][*]
  __shared__ float xs[256 * 20];   // row (g + 8c) holds xn channel g*32+c

#pragma unroll
  for (int p = 0; p < 32; ++p) {
    int ch = p * 8 + (TID >> 5);
    int cc = TID & 31;
    float wval = w[ch * 32 + cc];
    int row = (ch >> 3) + ((ch & 7) << 5);  // d + 32h
    w_s[row * 33 + cc] = wval;
  }
#pragma unroll
  for (int p = 0; p < 16; ++p) {
    int cc = p * 16 + (TID >> 4);
    int nl = TID & 15;
    float v = x[(size_t)(b * C + cc) * N + n0 + nl];
    float a = stats[C + cc] * gamma[cc];
    float xn = (v - stats[cc]) * a + beta[cc];
    int row = (cc >> 5) + ((cc & 31) << 3);  // g + 8c
    xs[row * 20 + nl] = xn;
  }
  __syncthreads();

  int d = TID & 31;
  int t2 = TID >> 5;  // n = n0 + t2*2 + {0,1}
#pragma unroll
  for (int h = 0; h < 8; ++h) {
    int g = (d * 8 + h) >> 5;
    const float* wrow = &w_s[(d + h * 32) * 33];
    float2 acc = {0.f, 0.f};
#pragma unroll
    for (int c = 0; c < 32; ++c) {
      float wv2 = wrow[c];
      float2 xv = *(const float2*)&xs[(g + c * 8) * 20 + t2 * 2];
      acc.x += wv2 * xv.x;
      acc.y += wv2 * xv.y;
    }
    int n = n0 + t2 * 2;
    size_t bh = (size_t)(b * 8 + h);
    if (proj < 2) {  // [bh][n][d]
      size_t o = (bh * N + n) * D + d;
      out[o] = (_Float16)acc.x;
      out[o + D] = (_Float16)acc.y;
    } else {         // [bh][d][n] (transposed)
      size_t o = (bh * D + d) * N + n;
      out[o] = (_Float16)acc.x;
      out[o + 1] = (_Float16)acc.y;
    }
  }
}

// ---------------- kernel 3: MFMA fp16 flash attention ----------------
// Block = 4 waves; wave owns 16 q rows. grid = 32 rowblocks x 16 bh x JS.
// S^T tile = mfma(A=K,B=Q): D col(lane&15)=q-row i, row((lane>>4)*4+r)=j-local.
// PV: O^T(dh) = mfma(A=V^T, B=P^T) accumulated over KV tiles with online softmax.
__global__ __launch_bounds__(256, 4) void k_attn(
    const _Float16* __restrict__ qa, const _Float16* __restrict__ ka,
    const _Float16* __restrict__ va, float* __restrict__ op,
    float* __restrict__ mp, float* __restrict__ lp, int JS) {
  int bid = blockIdx.x;
  int rb = bid & 31;
  int bh = (bid >> 5) & 15;
  int js = bid >> 9;
  int jrange = N / JS;
  int ntiles = jrange / 64;

  int w = TID >> 6;
  int lane = TID & 63;
  int il = lane & 15;   // q-row within wave block / frag row index
  int g = lane >> 4;    // 0..3

  __shared__ char Kc[4096];        // K tile [64 j][32 d] fp16, rows 64B, swz ^((j&3)<<4)
  __shared__ char Vc[4096];        // V^T tile [32 d][64 j] fp16, rows 128B, swz ^((d&7)<<4)
  __shared__ char Pc[4 * 2048];    // per-wave P^T [16 i][64 j] fp16, swz ^((i&7)<<4)
  char* Pw = Pc + w * 2048;

  int n_q = rb * 64 + w * 16 + il;
  h8 qf = *(const h8*)(qa + ((size_t)bh * N + n_q) * D + g * 8);

  f32x4 accO[2];
#pragma unroll
  for (int dh = 0; dh < 2; ++dh) accO[dh] = (f32x4){0.f, 0.f, 0.f, 0.f};
  float m = -3.0e38f, l = 0.f;

  // staging indices
  int kj = TID >> 2, kc = TID & 3;          // K: 64 rows x 4 chunks of 16B
  int vd = TID >> 3, vcc = TID & 7;         // Vt: 32 rows x 8 chunks of 16B
  const _Float16* kbase = ka + ((size_t)bh * N + (size_t)js * jrange + kj) * D + kc * 8;
  const _Float16* vbase = va + ((size_t)bh * D + vd) * N + (size_t)js * jrange + vcc * 8;
  int kdst = (kj * 64 + kc * 16) ^ ((kj & 3) << 4);
  int vdst = (vd * 128 + vcc * 16) ^ ((vd & 7) << 4);

  for (int t = 0; t < ntiles; ++t) {
    __syncthreads();
    *(h8*)(Kc + kdst) = *(const h8*)(kbase + (size_t)t * 64 * D);
    *(h8*)(Vc + vdst) = *(const h8*)(vbase + t * 64);
    __syncthreads();

    // ---- QK^T (S^T tiles), j covers 64 ----
    float pv[4][4];
    float tmax = -3.0e38f;
#pragma unroll
    for (int jt = 0; jt < 4; ++jt) {
      int krow = jt * 16 + il;
      h8 kf = *(const h8*)(Kc + ((krow * 64 + g * 16) ^ ((krow & 3) << 4)));
      f32x4 accS = (f32x4){0.f, 0.f, 0.f, 0.f};
      accS = __builtin_amdgcn_mfma_f32_16x16x32_f16(kf, qf, accS, 0, 0, 0);
#pragma unroll
      for (int r = 0; r < 4; ++r) {
        float xv = accS[r] * SCALE;
        pv[jt][r] = xv;
        tmax = fmaxf(tmax, xv);
      }
    }
    tmax = fmaxf(tmax, __shfl_xor(tmax, 16));
    tmax = fmaxf(tmax, __shfl_xor(tmax, 32));
    float mn = fmaxf(m, tmax);
    float corr = __expf(m - mn);
    float ls = 0.f;
#pragma unroll
    for (int jt = 0; jt < 4; ++jt)
#pragma unroll
      for (int r = 0; r < 4; ++r) {
        float e = __expf(pv[jt][r] - mn);
        pv[jt][r] = e;
        ls += e;
      }
    ls += __shfl_xor(ls, 16);
    ls += __shfl_xor(ls, 32);
    l = l * corr + ls;
    m = mn;
#pragma unroll
    for (int dh = 0; dh < 2; ++dh)
#pragma unroll
      for (int r = 0; r < 4; ++r) accO[dh][r] *= corr;

    // ---- P -> wave-private LDS (fp16, [16 i][64 j], swizzled) ----
#pragma unroll
    for (int jt = 0; jt < 4; ++jt) {
      h4 ph = {(_Float16)pv[jt][0], (_Float16)pv[jt][1],
               (_Float16)pv[jt][2], (_Float16)pv[jt][3]};
      *(h4*)(Pw + ((il * 128 + jt * 32 + g * 8) ^ ((il & 7) << 4))) = ph;
    }

    // ---- PV: O^T(dh) += V^T * P^T over 2 j-chunks of 32 ----
#pragma unroll
    for (int jb = 0; jb < 2; ++jb) {
      h8 pf = *(const h8*)(Pw + ((il * 128 + jb * 64 + g * 16) ^ ((il & 7) << 4)));
#pragma unroll
      for (int dh = 0; dh < 2; ++dh) {
        int vrow = dh * 16 + il;
        h8 vf = *(const h8*)(Vc + ((vrow * 128 + jb * 64 + g * 16) ^ ((vrow & 7) << 4)));
        accO[dh] = __builtin_amdgcn_mfma_f32_16x16x32_f16(vf, pf, accO[dh], 0, 0, 0);
      }
    }
  }

  // epilogue: lane holds O^T[d = dh*16+g*4+r][i=il] -> op[(js*BH+bh)][n][d]
  size_t obase = ((size_t)(js * BH + bh) * N + n_q) * D;
#pragma unroll
  for (int dh = 0; dh < 2; ++dh) {
    float4 o4 = {accO[dh][0], accO[dh][1], accO[dh][2], accO[dh][3]};
    *(float4*)(op + obase + dh * 16 + g * 4) = o4;
  }
  if (g == 0) {
    size_t idx = (size_t)(js * BH + bh) * N + n_q;
    mp[idx] = m;
    lp[idx] = l;
  }
}

// ---------------- kernel 4: combine j-split partials, normalize, transpose ----------------
__global__ __launch_bounds__(256) void k_combine(const float* __restrict__ op,
    const float* __restrict__ mp, const float* __restrict__ lp,
    float* __restrict__ ao, int JS) {
  int bh = blockIdx.x >> 3;
  int nc = blockIdx.x & 7;
  int n = nc * 256 + TID;
  int b = bh >> 3, h = bh & 7;
  float mv[4];
  float mg = -3.0e38f;
  for (int s = 0; s < JS; ++s) {
    mv[s] = mp[(size_t)(s * BH + bh) * N + n];
    mg = fmaxf(mg, mv[s]);
  }
  float wgt[4];
  float lg = 0.f;
  for (int s = 0; s < JS; ++s) {
    wgt[s] = __expf(mv[s] - mg);
    lg += wgt[s] * lp[(size_t)(s * BH + bh) * N + n];
  }
  float inv = 1.f / lg;
  for (int k = 0; k < 8; ++k) {
    float ox = 0.f, oy = 0.f, oz = 0.f, ow = 0.f;
    for (int s = 0; s < JS; ++s) {
      const float4 v = *(const float4*)(op + ((size_t)(s * BH + bh) * N + n) * D + k * 4);
      ox += wgt[s] * v.x; oy += wgt[s] * v.y; oz += wgt[s] * v.z; ow += wgt[s] * v.w;
    }
    size_t base = (size_t)(b * C + h * D + k * 4) * N + n;
    ao[base] = ox * inv;
    ao[base + N] = oy * inv;
    ao[base + 2 * N] = oz * inv;
    ao[base + 3 * N] = ow * inv;
  }
}

// ---------------- kernel 5: output 1x1 conv ----------------
__global__ __launch_bounds__(256) void k_final(const float* __restrict__ ao,
    const float* __restrict__ wo, const float* __restrict__ bo,
    float* __restrict__ out) {
  __shared__ float w_s[32 * 256];  // [o_local][c]
  __shared__ float a_s[256 * 32];  // [c][n_local]
  int nt = blockIdx.x & 63, oq = (blockIdx.x >> 6) & 7, b = blockIdx.x >> 9;
  int n0 = nt * 32, o0 = oq * 32;
#pragma unroll
  for (int p = 0; p < 8; ++p) {
    int idx = p * 256 + TID;
    int o_l = idx >> 6, c4 = idx & 63;
    ((float4*)w_s)[o_l * 64 + c4] = ((const float4*)wo)[(o0 + o_l) * 64 + c4];
  }
#pragma unroll
  for (int p = 0; p < 8; ++p) {
    int idx = p * 256 + TID;
    int c = idx >> 3, n4 = idx & 7;
    ((float4*)a_s)[c * 8 + n4] =
        *(const float4*)(ao + (size_t)(b * C + c) * N + n0 + n4 * 4);
  }
  __syncthreads();
  int n_l = TID & 31, og = TID >> 5;
  float acc[4] = {0.f, 0.f, 0.f, 0.f};
  for (int c = 0; c < 256; ++c) {
    float av = a_s[c * 32 + n_l];
#pragma unroll
    for (int k = 0; k < 4; ++k) acc[k] += w_s[(og * 4 + k) * 256 + c] * av;
  }
#pragma unroll
  for (int k = 0; k < 4; ++k) {
    int o = o0 + og * 4 + k;
    out[(size_t)(b * C + o) * N + n0 + n_l] = acc[k] + bo[o];
  }
}

extern "C" void kernel_launch(void* const* d_in, const int* in_sizes, int n_in,
                              void* d_out, int out_size, void* d_ws, size_t ws_size,
                              hipStream_t stream) {
  const float* x = (const float*)d_in[0];
  const float* gamma = (const float*)d_in[1];
  const float* beta = (const float*)d_in[2];
  const float* wk = (const float*)d_in[3];
  const float* wq = (const float*)d_in[4];
  const float* wv = (const float*)d_in[5];
  const float* wo = (const float*)d_in[6];
  const float* bo = (const float*)d_in[7];
  float* out = (float*)d_out;
  float* ws = (float*)d_ws;

  // bytes: stats 4096 | qkv 3*SZ*2 | op JS*SZ*4 | m,l JS*BH*N*8 | ao SZ*4
  auto need = [](int js) {
    return (size_t)4096 + 3 * SZ * 2 + (size_t)js * SZ * 4 +
           (size_t)js * BH * N * 8 + SZ * 4;
  };
  int JS = 4;
  while (JS > 1 && need(JS) > ws_size) JS >>= 1;

  float* stats = ws;
  _Float16* qa = (_Float16*)(ws + 1024);
  _Float16* ka = qa + SZ;
  _Float16* va = ka + SZ;
  float* op = (float*)(va + SZ);
  float* mp = op + (size_t)JS * SZ;
  float* lp = mp + (size_t)JS * BH * N;
  float* ao = lp + (size_t)JS * BH * N;

  k_bnstats<<<256, 256, 0, stream>>>(x, stats);
  k_proj<<<768, 256, 0, stream>>>(x, gamma, beta, wk, wq, wv, stats, qa, ka, va);
  k_attn<<<512 * JS, 256, 0, stream>>>(qa, ka, va, op, mp, lp, JS);
  k_combine<<<128, 256, 0, stream>>>(op, mp, lp, ao, JS);
  k_final<<<1024, 256, 0, stream>>>(ao, wo, bo, out);
}

// Round 5
// 89.138 us; speedup vs baseline: 2.9159x; 1.0008x over previous
//
#include <hip/hip_runtime.h>

#define TID threadIdx.x

constexpr int B = 2, C = 256, N = 2048, H = 8, D = 32, BH = 16;
constexpr float EPS = 1e-5f;
constexpr float SCALE = 0.17677669529663687f; // 32^-0.5
constexpr size_t SZ = (size_t)BH * N * D;     // 1048576 elements per Q/K/V buffer

typedef _Float16 h8 __attribute__((ext_vector_type(8)));
typedef _Float16 h4 __attribute__((ext_vector_type(4)));
typedef float f32x4 __attribute__((ext_vector_type(4)));

// ---------------- kernel 1: batchnorm stats (mean, rstd per channel) ----------------
__global__ __launch_bounds__(256) void k_bnstats(const float* __restrict__ x,
                                                 float* __restrict__ stats) {
  int c = blockIdx.x;
  float s = 0.f, ss = 0.f;
  const float4* x4 = (const float4*)x;
  for (int k = 0; k < B; ++k) {
    const float4* p = x4 + (size_t)(k * C + c) * (N / 4);
    for (int i = TID; i < N / 4; i += 256) {
      float4 v = p[i];
      s += v.x + v.y + v.z + v.w;
      ss += v.x * v.x + v.y * v.y + v.z * v.z + v.w * v.w;
    }
  }
#pragma unroll
  for (int off = 32; off; off >>= 1) {
    s += __shfl_down(s, off);
    ss += __shfl_down(ss, off);
  }
  __shared__ float red[8];
  int w = TID >> 6;
  if ((TID & 63) == 0) { red[w] = s; red[4 + w] = ss; }
  __syncthreads();
  if (TID == 0) {
    float S = red[0] + red[1] + red[2] + red[3];
    float SS = red[4] + red[5] + red[6] + red[7];
    float mean = S * (1.f / (B * N));
    float var = SS * (1.f / (B * N)) - mean * mean;
    stats[c] = mean;
    stats[C + c] = rsqrtf(var + EPS);
  }
}

// ---------------- kernel 2: fused BN-apply + grouped conv projections (fp16 out) --------
// All of Qa/Ka/Va: fp16 [bh][n][d] (coalesced). Channel-split quirk + q/k swap applied.
__global__ __launch_bounds__(256) void k_proj(const float* __restrict__ x,
    const float* __restrict__ gamma, const float* __restrict__ beta,
    const float* __restrict__ wk, const float* __restrict__ wq,
    const float* __restrict__ wv, const float* __restrict__ stats,
    _Float16* __restrict__ qa, _Float16* __restrict__ ka, _Float16* __restrict__ va) {
  int proj = blockIdx.x >> 8;
  int rem = blockIdx.x & 255;
  int b = rem >> 7;
  int n0 = (rem & 127) * 16;
  const float* w = proj == 0 ? wk : (proj == 1 ? wq : wv);
  _Float16* out = proj == 0 ? qa : (proj == 1 ? ka : va);

  __shared__ float w_s[256 * 33];  // row (d + 32h) holds w[8d+h][*]
  __shared__ float xs[256 * 20];   // row (g + 8c) holds xn channel g*32+c

#pragma unroll
  for (int p = 0; p < 32; ++p) {
    int ch = p * 8 + (TID >> 5);
    int cc = TID & 31;
    float wval = w[ch * 32 + cc];
    int row = (ch >> 3) + ((ch & 7) << 5);  // d + 32h
    w_s[row * 33 + cc] = wval;
  }
#pragma unroll
  for (int p = 0; p < 16; ++p) {
    int cc = p * 16 + (TID >> 4);
    int nl = TID & 15;
    float v = x[(size_t)(b * C + cc) * N + n0 + nl];
    float a = stats[C + cc] * gamma[cc];
    float xn = (v - stats[cc]) * a + beta[cc];
    int row = (cc >> 5) + ((cc & 31) << 3);  // g + 8c
    xs[row * 20 + nl] = xn;
  }
  __syncthreads();

  int d = TID & 31;
  int t2 = TID >> 5;  // n = n0 + t2*2 + {0,1}
#pragma unroll
  for (int h = 0; h < 8; ++h) {
    int g = (d * 8 + h) >> 5;
    const float* wrow = &w_s[(d + h * 32) * 33];
    float2 acc = {0.f, 0.f};
#pragma unroll
    for (int c = 0; c < 32; ++c) {
      float wv2 = wrow[c];
      float2 xv = *(const float2*)&xs[(g + c * 8) * 20 + t2 * 2];
      acc.x += wv2 * xv.x;
      acc.y += wv2 * xv.y;
    }
    int n = n0 + t2 * 2;
    size_t bh = (size_t)(b * 8 + h);
    size_t o = (bh * N + n) * D + d;
    out[o] = (_Float16)acc.x;
    out[o + D] = (_Float16)acc.y;
  }
}

// ---------------- kernel 3: MFMA fp16 flash attention, reg-prefetch double-buffer --------
// Block = 4 waves; wave owns 16 q rows. grid = 32 rowblocks x 16 bh x JS.
// S^T tile = mfma(A=K,B=Q). PV: O^T = mfma(A=V^T, B=P^T), V transposed during LDS staging.
__global__ __launch_bounds__(256, 4) void k_attn(
    const _Float16* __restrict__ qa, const _Float16* __restrict__ ka,
    const _Float16* __restrict__ va, float* __restrict__ op,
    float* __restrict__ mp, float* __restrict__ lp, int JS) {
  int bid = blockIdx.x;
  int rb = bid & 31;
  int bh = (bid >> 5) & 15;
  int js = bid >> 9;
  int jrange = N / JS;
  int ntiles = jrange / 64;

  int w = TID >> 6;
  int lane = TID & 63;
  int il = lane & 15;   // q-row within wave block / frag row index
  int g = lane >> 4;    // 0..3

  __shared__ char Kc[4096];        // K tile [64 j][32 d] fp16, rows 64B, swz ^((j&3)<<4)
  __shared__ char Vc[4096];        // V^T tile [32 d][64 j] fp16, rows 128B, swz f(d)
  __shared__ char Pc[4 * 2048];    // per-wave P^T [16 i][64 j] fp16, swz ^((i&7)<<4)
  char* Pw = Pc + w * 2048;

  int n_q = rb * 64 + w * 16 + il;
  h8 qf = *(const h8*)(qa + ((size_t)bh * N + n_q) * D + g * 8);

  f32x4 accO[2];
#pragma unroll
  for (int dh = 0; dh < 2; ++dh) accO[dh] = (f32x4){0.f, 0.f, 0.f, 0.f};
  float m = -3.0e38f, l = 0.f;

  // staging: thread covers K row kj (j), 16B chunk kc (8 d's); V same source pattern
  int kj = TID >> 2, kc = TID & 3;
  const _Float16* kbase = ka + ((size_t)bh * N + (size_t)js * jrange + kj) * D + kc * 8;
  const _Float16* vbase = va + ((size_t)bh * N + (size_t)js * jrange + kj) * D + kc * 8;
  int kdst = (kj * 64 + kc * 16) ^ ((kj & 3) << 4);

  h8 kreg = *(const h8*)kbase;
  h8 vreg = *(const h8*)vbase;

  for (int t = 0; t < ntiles; ++t) {
    __syncthreads();
    *(h8*)(Kc + kdst) = kreg;
    // V transpose-scatter: element e -> row d = kc*8+e, col j = kj
#pragma unroll
    for (int e = 0; e < 8; ++e) {
      int d = kc * 8 + e;
      int addr = (d * 128 + kj * 2) ^ ((d & 7) << 4) ^ (((d >> 3) & 3) << 5);
      *(_Float16*)(Vc + addr) = vreg[e];
    }
    if (t + 1 < ntiles) {  // prefetch next tile while computing this one
      kreg = *(const h8*)(kbase + (size_t)(t + 1) * 64 * D);
      vreg = *(const h8*)(vbase + (size_t)(t + 1) * 64 * D);
    }
    __syncthreads();

    // ---- QK^T (S^T tiles), j covers 64 ----
    float pv[4][4];
    float tmax = -3.0e38f;
#pragma unroll
    for (int jt = 0; jt < 4; ++jt) {
      int krow = jt * 16 + il;
      h8 kf = *(const h8*)(Kc + ((krow * 64 + g * 16) ^ ((krow & 3) << 4)));
      f32x4 accS = (f32x4){0.f, 0.f, 0.f, 0.f};
      accS = __builtin_amdgcn_mfma_f32_16x16x32_f16(kf, qf, accS, 0, 0, 0);
#pragma unroll
      for (int r = 0; r < 4; ++r) {
        float xv = accS[r] * SCALE;
        pv[jt][r] = xv;
        tmax = fmaxf(tmax, xv);
      }
    }
    tmax = fmaxf(tmax, __shfl_xor(tmax, 16));
    tmax = fmaxf(tmax, __shfl_xor(tmax, 32));
    float mn = fmaxf(m, tmax);
    float corr = __expf(m - mn);
    float ls = 0.f;
#pragma unroll
    for (int jt = 0; jt < 4; ++jt)
#pragma unroll
      for (int r = 0; r < 4; ++r) {
        float e = __expf(pv[jt][r] - mn);
        pv[jt][r] = e;
        ls += e;
      }
    ls += __shfl_xor(ls, 16);
    ls += __shfl_xor(ls, 32);
    l = l * corr + ls;
    m = mn;
#pragma unroll
    for (int dh = 0; dh < 2; ++dh)
#pragma unroll
      for (int r = 0; r < 4; ++r) accO[dh][r] *= corr;

    // ---- P -> wave-private LDS (fp16, [16 i][64 j], swizzled) ----
#pragma unroll
    for (int jt = 0; jt < 4; ++jt) {
      h4 ph = {(_Float16)pv[jt][0], (_Float16)pv[jt][1],
               (_Float16)pv[jt][2], (_Float16)pv[jt][3]};
      *(h4*)(Pw + ((il * 128 + jt * 32 + g * 8) ^ ((il & 7) << 4))) = ph;
    }

    // ---- PV: O^T(dh) += V^T * P^T over 2 j-chunks of 32 ----
#pragma unroll
    for (int jb = 0; jb < 2; ++jb) {
      h8 pf = *(const h8*)(Pw + ((il * 128 + jb * 64 + g * 16) ^ ((il & 7) << 4)));
#pragma unroll
      for (int dh = 0; dh < 2; ++dh) {
        int vrow = dh * 16 + il;
        int vaddr = (vrow * 128 + jb * 64 + g * 16) ^ ((vrow & 7) << 4) ^
                    (((vrow >> 3) & 3) << 5);
        h8 vf = *(const h8*)(Vc + vaddr);
        accO[dh] = __builtin_amdgcn_mfma_f32_16x16x32_f16(vf, pf, accO[dh], 0, 0, 0);
      }
    }
  }

  // epilogue: lane holds O^T[d = dh*16+g*4+r][i=il] -> op[(js*BH+bh)][n][d]
  size_t obase = ((size_t)(js * BH + bh) * N + n_q) * D;
#pragma unroll
  for (int dh = 0; dh < 2; ++dh) {
    float4 o4 = {accO[dh][0], accO[dh][1], accO[dh][2], accO[dh][3]};
    *(float4*)(op + obase + dh * 16 + g * 4) = o4;
  }
  if (g == 0) {
    size_t idx = (size_t)(js * BH + bh) * N + n_q;
    mp[idx] = m;
    lp[idx] = l;
  }
}

// ---------------- kernel 4: combine j-split partials, normalize, transpose ----------------
__global__ __launch_bounds__(256) void k_combine(const float* __restrict__ op,
    const float* __restrict__ mp, const float* __restrict__ lp,
    float* __restrict__ ao, int JS) {
  int bh = blockIdx.x >> 3;
  int nc = blockIdx.x & 7;
  int n = nc * 256 + TID;
  int b = bh >> 3, h = bh & 7;
  float mv[4];
  float mg = -3.0e38f;
  for (int s = 0; s < JS; ++s) {
    mv[s] = mp[(size_t)(s * BH + bh) * N + n];
    mg = fmaxf(mg, mv[s]);
  }
  float wgt[4];
  float lg = 0.f;
  for (int s = 0; s < JS; ++s) {
    wgt[s] = __expf(mv[s] - mg);
    lg += wgt[s] * lp[(size_t)(s * BH + bh) * N + n];
  }
  float inv = 1.f / lg;
  for (int k = 0; k < 8; ++k) {
    float ox = 0.f, oy = 0.f, oz = 0.f, ow = 0.f;
    for (int s = 0; s < JS; ++s) {
      const float4 v = *(const float4*)(op + ((size_t)(s * BH + bh) * N + n) * D + k * 4);
      ox += wgt[s] * v.x; oy += wgt[s] * v.y; oz += wgt[s] * v.z; ow += wgt[s] * v.w;
    }
    size_t base = (size_t)(b * C + h * D + k * 4) * N + n;
    ao[base] = ox * inv;
    ao[base + N] = oy * inv;
    ao[base + 2 * N] = oz * inv;
    ao[base + 3 * N] = ow * inv;
  }
}

// ---------------- kernel 5: output 1x1 conv ----------------
__global__ __launch_bounds__(256) void k_final(const float* __restrict__ ao,
    const float* __restrict__ wo, const float* __restrict__ bo,
    float* __restrict__ out) {
  __shared__ float w_s[32 * 256];  // [o_local][c]
  __shared__ float a_s[256 * 32];  // [c][n_local]
  int nt = blockIdx.x & 63, oq = (blockIdx.x >> 6) & 7, b = blockIdx.x >> 9;
  int n0 = nt * 32, o0 = oq * 32;
#pragma unroll
  for (int p = 0; p < 8; ++p) {
    int idx = p * 256 + TID;
    int o_l = idx >> 6, c4 = idx & 63;
    ((float4*)w_s)[o_l * 64 + c4] = ((const float4*)wo)[(o0 + o_l) * 64 + c4];
  }
#pragma unroll
  for (int p = 0; p < 8; ++p) {
    int idx = p * 256 + TID;
    int c = idx >> 3, n4 = idx & 7;
    ((float4*)a_s)[c * 8 + n4] =
        *(const float4*)(ao + (size_t)(b * C + c) * N + n0 + n4 * 4);
  }
  __syncthreads();
  int n_l = TID & 31, og = TID >> 5;
  float acc[4] = {0.f, 0.f, 0.f, 0.f};
  for (int c = 0; c < 256; ++c) {
    float av = a_s[c * 32 + n_l];
#pragma unroll
    for (int k = 0; k < 4; ++k) acc[k] += w_s[(og * 4 + k) * 256 + c] * av;
  }
#pragma unroll
  for (int k = 0; k < 4; ++k) {
    int o = o0 + og * 4 + k;
    out[(size_t)(b * C + o) * N + n0 + n_l] = acc[k] + bo[o];
  }
}

extern "C" void kernel_launch(void* const* d_in, const int* in_sizes, int n_in,
                              void* d_out, int out_size, void* d_ws, size_t ws_size,
                              hipStream_t stream) {
  const float* x = (const float*)d_in[0];
  const float* gamma = (const float*)d_in[1];
  const float* beta = (const float*)d_in[2];
  const float* wk = (const float*)d_in[3];
  const float* wq = (const float*)d_in[4];
  const float* wv = (const float*)d_in[5];
  const float* wo = (const float*)d_in[6];
  const float* bo = (const float*)d_in[7];
  float* out = (float*)d_out;
  float* ws = (float*)d_ws;

  // bytes: stats 4096 | qkv 3*SZ*2 | op JS*SZ*4 | m,l JS*BH*N*8 | ao SZ*4
  auto need = [](int js) {
    return (size_t)4096 + 3 * SZ * 2 + (size_t)js * SZ * 4 +
           (size_t)js * BH * N * 8 + SZ * 4;
  };
  int JS = 2;
  while (JS > 1 && need(JS) > ws_size) JS >>= 1;

  float* stats = ws;
  _Float16* qa = (_Float16*)(ws + 1024);
  _Float16* ka = qa + SZ;
  _Float16* va = ka + SZ;
  float* op = (float*)(va + SZ);
  float* mp = op + (size_t)JS * SZ;
  float* lp = mp + (size_t)JS * BH * N;
  float* ao = lp + (size_t)JS * BH * N;

  k_bnstats<<<256, 256, 0, stream>>>(x, stats);
  k_proj<<<768, 256, 0, stream>>>(x, gamma, beta, wk, wq, wv, stats, qa, ka, va);
  k_attn<<<512 * JS, 256, 0, stream>>>(qa, ka, va, op, mp, lp, JS);
  k_combine<<<128, 256, 0, stream>>>(op, mp, lp, ao, JS);
  k_final<<<1024, 256, 0, stream>>>(ao, wo, bo, out);
}